// Round 2
// baseline (478.186 us; speedup 1.0000x reference)
//
#include <hip/hip_runtime.h>

#define BB 4
#define LL 2048
#define DD 1024
#define HH 16
#define HD 64

typedef __attribute__((ext_vector_type(8))) short s16x8;
typedef __attribute__((ext_vector_type(4))) short s16x4;
typedef __attribute__((ext_vector_type(4))) float f32x4;

__device__ __forceinline__ short f2bf(float f) {
  union { float f; unsigned u; } c;
  c.f = f;
  return (short)((c.u + 0x7fffu + ((c.u >> 16) & 1u)) >> 16);  // RNE
}

// async global -> LDS, 16B per lane. LDS dest = wave-uniform base + lane*16.
__device__ __forceinline__ void cp16(const void* g, void* l) {
  __builtin_amdgcn_global_load_lds(
      (const __attribute__((address_space(1))) void*)g,
      (__attribute__((address_space(3))) void*)l, 16, 0, 0);
}

// ---------------- fp32 -> bf16 convert ----------------
__global__ __launch_bounds__(256) void f2b_kernel(const float* __restrict__ in,
                                                  short* __restrict__ out, int n4) {
  int i = blockIdx.x * blockDim.x + threadIdx.x;
  if (i >= n4) return;
  float4 v = ((const float4*)in)[i];
  s16x4 o;
  o[0] = f2bf(v.x);
  o[1] = f2bf(v.y);
  o[2] = f2bf(v.z);
  o[3] = f2bf(v.w);
  ((s16x4*)out)[i] = o;
}

// ---------------- GEMM: C[M,N] = A[M,K] * B[N,K]^T (bf16 in, MFMA) ----------
// MODE 0: scatter bf16 into Q/K [B,H,L,HD] and V transposed [B,H,HD,L].
// MODE 1: fp32 row-major out.
template <int MODE>
__global__ __launch_bounds__(256) void gemm_bt(const short* __restrict__ A,
                                               const short* __restrict__ Bm,
                                               int K, int N,
                                               short* __restrict__ qo,
                                               short* __restrict__ ko,
                                               short* __restrict__ vo,
                                               float* __restrict__ fo) {
  __shared__ __align__(16) short As[128 * 32];
  __shared__ __align__(16) short Bs[128 * 32];
  const int tid = threadIdx.x;
  const int m0 = blockIdx.y * 128, n0 = blockIdx.x * 128;
  const int wave = tid >> 6, lane = tid & 63;
  const int quad = lane >> 4, c16 = lane & 15;
  const int wr = (wave >> 1) * 64, wc = (wave & 1) * 64;

  f32x4 zero = {0.f, 0.f, 0.f, 0.f};
  f32x4 acc[4][4];
#pragma unroll
  for (int i = 0; i < 4; i++)
#pragma unroll
    for (int j = 0; j < 4; j++) acc[i][j] = zero;

  const int row1 = tid >> 2, seg = (tid & 3) * 8;  // 64 rows x 4 16B-segments
  const short* Ag = A + (size_t)(m0 + row1) * K + seg;
  const short* Bg = Bm + (size_t)(n0 + row1) * K + seg;

  for (int k0 = 0; k0 < K; k0 += 32) {
    __syncthreads();  // protect LDS from previous iteration's readers
    cp16(Ag + k0, As + wave * 512);
    cp16(Ag + (size_t)64 * K + k0, As + 2048 + wave * 512);
    cp16(Bg + k0, Bs + wave * 512);
    cp16(Bg + (size_t)64 * K + k0, Bs + 2048 + wave * 512);
    __syncthreads();  // drains vmcnt before barrier
    s16x8 af[4], bf[4];
#pragma unroll
    for (int i = 0; i < 4; i++)
      af[i] = *(const s16x8*)&As[(wr + i * 16 + c16) * 32 + quad * 8];
#pragma unroll
    for (int j = 0; j < 4; j++)
      bf[j] = *(const s16x8*)&Bs[(wc + j * 16 + c16) * 32 + quad * 8];
#pragma unroll
    for (int i = 0; i < 4; i++)
#pragma unroll
      for (int j = 0; j < 4; j++)
        acc[i][j] = __builtin_amdgcn_mfma_f32_16x16x32_bf16(af[i], bf[j], acc[i][j], 0, 0, 0);
  }

  if (MODE == 0) {
#pragma unroll
    for (int j = 0; j < 4; j++) {
      const int gn = n0 + wc + j * 16 + c16;       // 0..3071
      const int which = gn >> 10;
      const int h = (gn >> 6) & 15;
      const int hd = gn & 63;
      if (which == 2) {
#pragma unroll
        for (int i = 0; i < 4; i++)
#pragma unroll
          for (int r = 0; r < 4; r++) {
            const int gm = m0 + wr + i * 16 + quad * 4 + r;
            const int b = gm >> 11, l = gm & 2047;
            vo[((size_t)((b << 4) + h) * HD + hd) * LL + l] = f2bf(acc[i][j][r]);
          }
      } else {
        short* dst = which == 0 ? qo : ko;
#pragma unroll
        for (int i = 0; i < 4; i++)
#pragma unroll
          for (int r = 0; r < 4; r++) {
            const int gm = m0 + wr + i * 16 + quad * 4 + r;
            const int b = gm >> 11, l = gm & 2047;
            dst[((size_t)((b << 4) + h) * LL + l) * HD + hd] = f2bf(acc[i][j][r]);
          }
      }
    }
  } else {
#pragma unroll
    for (int i = 0; i < 4; i++)
#pragma unroll
      for (int r = 0; r < 4; r++) {
        const int gm = m0 + wr + i * 16 + quad * 4 + r;
#pragma unroll
        for (int j = 0; j < 4; j++) {
          const int gn = n0 + wc + j * 16 + c16;
          fo[(size_t)gm * N + gn] = acc[i][j][r];
        }
      }
  }
}

// ---------------- flash attention: 4 waves/block, 64-query tile ------------
// K staged [key][hd], V staged [hd][key] (from transposed V), both via
// global_load_lds. Each wave owns 16 queries; K-blocks of 64 shared in LDS.
#define SCALE_LOG2E 0.18033688011112042f  // 0.125 * log2(e)

__global__ __launch_bounds__(256) void attn_kernel(const short* __restrict__ Qb,
                                                   const short* __restrict__ Kb,
                                                   const short* __restrict__ Vtb,
                                                   short* __restrict__ Cb) {
  const int qt = gridDim.x - 1 - blockIdx.x;  // heavy tiles dispatched first
  const int bh = blockIdx.y;                  // 0..63
  const int tid = threadIdx.x;
  const int wave = tid >> 6, lane = tid & 63;
  const int quad = lane >> 4, c16 = lane & 15;
  const size_t base = (size_t)bh * LL * HD;
  const short* Q = Qb + base;
  const short* K = Kb + base;
  const short* Vt = Vtb + base;  // [HD][LL]
  const int q0 = qt * 64;
  const int qw = q0 + wave * 16;  // this wave's 16 queries
  const float NEG_INF = -__builtin_inff();

  __shared__ __align__(16) short Ks[64 * 64];    // [key][hd]
  __shared__ __align__(16) short Vs[64 * 64];    // [hd][key]
  __shared__ __align__(16) short Ps[4][16 * 68]; // per-wave P, padded stride

  s16x8 qf[2];
#pragma unroll
  for (int s = 0; s < 2; s++)
    qf[s] = *(const s16x8*)(Q + (size_t)(qw + c16) * HD + s * 32 + quad * 8);

  f32x4 zero = {0.f, 0.f, 0.f, 0.f};
  f32x4 o[4];
#pragma unroll
  for (int j = 0; j < 4; j++) o[j] = zero;
  float m_i[4], l_i[4];
#pragma unroll
  for (int r = 0; r < 4; r++) { m_i[r] = NEG_INF; l_i[r] = 0.f; }

  const int srow = tid >> 3, scol = (tid & 7) * 8;  // staging: 32 rows/issue
  const int kend_w = qw + 16;
  const int kend_b = q0 + 64;

  for (int kb = 0; kb < kend_b; kb += 64) {
    __syncthreads();  // previous iteration's readers done
    cp16(K + (size_t)(kb + srow) * HD + scol, Ks + wave * 512);
    cp16(K + (size_t)(kb + 32 + srow) * HD + scol, Ks + 2048 + wave * 512);
    cp16(Vt + (size_t)srow * LL + kb + scol, Vs + wave * 512);
    cp16(Vt + (size_t)(32 + srow) * LL + kb + scol, Vs + 2048 + wave * 512);
    __syncthreads();  // drain async copies
    if (kb >= kend_w) continue;  // wave-uniform; barriers balanced at loop top

    // ---- QK^T: 16 queries x 64 keys ----
    f32x4 s[4];
#pragma unroll
    for (int j = 0; j < 4; j++) s[j] = zero;
#pragma unroll
    for (int ks = 0; ks < 2; ks++)
#pragma unroll
      for (int j = 0; j < 4; j++) {
        s16x8 kf = *(const s16x8*)&Ks[(j * 16 + c16) * 64 + ks * 32 + quad * 8];
        s[j] = __builtin_amdgcn_mfma_f32_16x16x32_bf16(qf[ks], kf, s[j], 0, 0, 0);
      }

    // ---- online softmax (exp2 domain) ----
    const bool need_mask = (kb + 64 > qw);  // wave-uniform
#pragma unroll
    for (int r = 0; r < 4; r++) {
      const int qrow = qw + quad * 4 + r;
      float v[4];
#pragma unroll
      for (int j = 0; j < 4; j++) {
        v[j] = s[j][r] * SCALE_LOG2E;
        if (need_mask && (kb + j * 16 + c16 > qrow)) v[j] = NEG_INF;
      }
      float mx = fmaxf(fmaxf(v[0], v[1]), fmaxf(v[2], v[3]));
      mx = fmaxf(mx, __shfl_xor(mx, 1));
      mx = fmaxf(mx, __shfl_xor(mx, 2));
      mx = fmaxf(mx, __shfl_xor(mx, 4));
      mx = fmaxf(mx, __shfl_xor(mx, 8));
      const float mnew = fmaxf(m_i[r], mx);
      const float alpha = exp2f(m_i[r] - mnew);
      m_i[r] = mnew;
      float p[4], sum = 0.f;
#pragma unroll
      for (int j = 0; j < 4; j++) {
        p[j] = exp2f(v[j] - mnew);
        sum += p[j];
      }
#pragma unroll
      for (int j = 0; j < 4; j++)
        Ps[wave][(quad * 4 + r) * 68 + j * 16 + c16] = f2bf(p[j]);
      sum += __shfl_xor(sum, 1);
      sum += __shfl_xor(sum, 2);
      sum += __shfl_xor(sum, 4);
      sum += __shfl_xor(sum, 8);
      l_i[r] = l_i[r] * alpha + sum;
#pragma unroll
      for (int j = 0; j < 4; j++) o[j][r] *= alpha;
    }

    // ---- PV: P[16x64] * V[64keys x 64hd] ----
    s16x8 pa0 = *(const s16x8*)&Ps[wave][c16 * 68 + quad * 8];
    s16x8 pa1 = *(const s16x8*)&Ps[wave][c16 * 68 + 32 + quad * 8];
#pragma unroll
    for (int j4 = 0; j4 < 4; j4++) {
      s16x8 vf0 = *(const s16x8*)&Vs[(j4 * 16 + c16) * 64 + quad * 8];
      s16x8 vf1 = *(const s16x8*)&Vs[(j4 * 16 + c16) * 64 + 32 + quad * 8];
      o[j4] = __builtin_amdgcn_mfma_f32_16x16x32_bf16(pa0, vf0, o[j4], 0, 0, 0);
      o[j4] = __builtin_amdgcn_mfma_f32_16x16x32_bf16(pa1, vf1, o[j4], 0, 0, 0);
    }
  }

  const int b = bh >> 4, h = bh & 15;
#pragma unroll
  for (int r = 0; r < 4; r++) {
    const float inv = 1.0f / l_i[r];
    const int qrow = qw + quad * 4 + r;
#pragma unroll
    for (int j4 = 0; j4 < 4; j4++)
      Cb[(size_t)(b * LL + qrow) * DD + h * HD + j4 * 16 + c16] =
          f2bf(o[j4][r] * inv);
  }
}

// ---------------- launch ----------------
extern "C" void kernel_launch(void* const* d_in, const int* in_sizes, int n_in,
                              void* d_out, int out_size, void* d_ws, size_t ws_size,
                              hipStream_t stream) {
  const float* x = (const float*)d_in[0];
  const float* wqkv = (const float*)d_in[1];
  const float* wout = (const float*)d_in[2];
  float* out = (float*)d_out;

  const size_t NX = (size_t)BB * LL * DD;  // 8388608
  short* xb = (short*)d_ws;
  short* wqkvb = xb + NX;
  short* woutb = wqkvb + (size_t)3 * DD * DD;
  short* qb = woutb + (size_t)DD * DD;
  short* kb = qb + NX;
  short* vb = kb + NX;   // V transposed: [B,H,HD,L]
  short* cb = vb + NX;
  // total: 92,274,688 bytes of d_ws

  f2b_kernel<<<dim3((unsigned)(NX / 4 / 256)), 256, 0, stream>>>(x, xb, (int)(NX / 4));
  f2b_kernel<<<dim3(3 * DD * DD / 4 / 256), 256, 0, stream>>>(wqkv, wqkvb, 3 * DD * DD / 4);
  f2b_kernel<<<dim3(DD * DD / 4 / 256), 256, 0, stream>>>(wout, woutb, DD * DD / 4);

  gemm_bt<0><<<dim3(3 * DD / 128, BB * LL / 128), 256, 0, stream>>>(
      xb, wqkvb, DD, 3 * DD, qb, kb, vb, nullptr);
  attn_kernel<<<dim3(LL / 64, BB * HH), 256, 0, stream>>>(qb, kb, vb, cb);
  gemm_bt<1><<<dim3(DD / 128, BB * LL / 128), 256, 0, stream>>>(
      cb, woutb, DD, DD, nullptr, nullptr, nullptr, out);
}